// Round 1
// baseline (559.550 us; speedup 1.0000x reference)
//
#include <hip/hip_runtime.h>
#include <stdint.h>

#define TTOK 4096
#define DM   1024
#define FF   2048
#define NE   8

typedef __attribute__((ext_vector_type(8))) short short8;
typedef __attribute__((ext_vector_type(8))) unsigned short ushort8;
typedef __attribute__((ext_vector_type(4))) float f32x4;

// ---------------- workspace layout (bytes) ----------------
#define OFF_XB      0ull
#define OFF_WS1T    (OFF_XB      + (size_t)TTOK*DM*2)
#define OFF_WS3T    (OFF_WS1T    + (size_t)FF*DM*2)
#define OFF_WS2T    (OFF_WS3T    + (size_t)FF*DM*2)
#define OFF_WE1T    (OFF_WS2T    + (size_t)DM*FF*2)
#define OFF_WE3T    (OFF_WE1T    + (size_t)NE*FF*DM*2)
#define OFF_WE2T    (OFF_WE3T    + (size_t)NE*FF*DM*2)
#define OFF_HSH     (OFF_WE2T    + (size_t)NE*DM*FF*2)
#define OFF_HRT     (OFF_HSH     + (size_t)TTOK*FF*2)
#define OFF_CONTRIB (OFF_HRT     + (size_t)2*TTOK*FF*2)
#define OFF_TOPKW   (OFF_CONTRIB + (size_t)2*TTOK*DM*4)
#define OFF_TOPKI   (OFF_TOPKW   + (size_t)TTOK*2*4)
#define OFF_SLOTTOK (OFF_TOPKI   + (size_t)TTOK*2*4)
#define OFF_TOKSLOT (OFF_SLOTTOK + (size_t)TTOK*2*4)
#define OFF_COUNTS  (OFF_TOKSLOT + (size_t)TTOK*2*4)
#define WS_NEEDED   (OFF_COUNTS + 256)

__device__ __forceinline__ unsigned short f2bf(float f) {
  unsigned u = __float_as_uint(f);
  return (unsigned short)((u + 0x7FFFu + ((u >> 16) & 1u)) >> 16);
}

__device__ __forceinline__ void async16(const void* g, void* l) {
  __builtin_amdgcn_global_load_lds(
      (const __attribute__((address_space(1))) void*)g,
      (__attribute__((address_space(3))) void*)l, 16, 0, 0);
}

// ---------------- small kernels ----------------
__global__ void k_zero(int* p, int n) {
  int i = threadIdx.x;
  if (i < n) p[i] = 0;
}

// one wave per token: fp32 gate logits, sigmoid, top-2, normalized weights
__global__ void k_gate(const float* __restrict__ x, const float* __restrict__ Wg,
                       float* __restrict__ topkw, int* __restrict__ topki,
                       int* __restrict__ counts) {
  int wave = threadIdx.x >> 6;
  int lane = threadIdx.x & 63;
  int t = blockIdx.x * 4 + wave;
  float acc[NE];
#pragma unroll
  for (int e = 0; e < NE; e++) acc[e] = 0.f;
  const float* xr = x + (size_t)t * DM;
  for (int i = 0; i < DM / 64; i++) {
    int k = lane + i * 64;
    float xv = xr[k];
    const float* wr = Wg + (size_t)k * NE;
#pragma unroll
    for (int e = 0; e < NE; e++) acc[e] += xv * wr[e];
  }
#pragma unroll
  for (int e = 0; e < NE; e++) {
#pragma unroll
    for (int off = 32; off >= 1; off >>= 1) acc[e] += __shfl_xor(acc[e], off, 64);
  }
  if (lane == 0) {
    float g[NE];
#pragma unroll
    for (int e = 0; e < NE; e++) g[e] = 1.f / (1.f + __expf(-acc[e]));
    int i1 = -1, i2 = -1;
    float m1 = -1e30f, m2 = -1e30f;
#pragma unroll
    for (int e = 0; e < NE; e++) {
      float v = g[e];
      if (v > m1) { m2 = m1; i2 = i1; m1 = v; i1 = e; }
      else if (v > m2) { m2 = v; i2 = e; }
    }
    float s = m1 + m2;
    topkw[t * 2 + 0] = m1 / s;
    topkw[t * 2 + 1] = m2 / s;
    topki[t * 2 + 0] = i1;
    topki[t * 2 + 1] = i2;
    atomicAdd(&counts[i1], 1);
    atomicAdd(&counts[i2], 1);
  }
}

__global__ void k_offsets(const int* __restrict__ counts, int* __restrict__ offs) {
  if (threadIdx.x == 0 && blockIdx.x == 0) {
    int s = 0;
    for (int e = 0; e < NE; e++) { offs[e] = s; s += counts[e]; }
  }
}

__global__ void k_fill(const int* __restrict__ topki, const int* __restrict__ offs,
                       int* __restrict__ fills, int* __restrict__ slot_token,
                       int* __restrict__ token_slot) {
  int t = blockIdx.x * 256 + threadIdx.x;
  if (t >= TTOK) return;
#pragma unroll
  for (int k = 0; k < 2; k++) {
    int e = topki[t * 2 + k];
    int pos = atomicAdd(&fills[e], 1);
    int slot = offs[e] + pos;
    slot_token[slot] = t;
    token_slot[t * 2 + k] = slot;
  }
}

__global__ void k_cvt_x(const float* __restrict__ x, unsigned short* __restrict__ xb) {
  size_t i = (size_t)(blockIdx.x * 256 + threadIdx.x) * 8;
  f32x4 a = *(const f32x4*)(x + i);
  f32x4 b = *(const f32x4*)(x + i + 4);
  ushort8 o;
  o[0] = f2bf(a[0]); o[1] = f2bf(a[1]); o[2] = f2bf(a[2]); o[3] = f2bf(a[3]);
  o[4] = f2bf(b[0]); o[5] = f2bf(b[1]); o[6] = f2bf(b[2]); o[7] = f2bf(b[3]);
  *(ushort8*)(xb + i) = o;
}

// in [B][R][C] f32 -> out [B][C][R] bf16
__global__ void k_transpose(const float* __restrict__ in, unsigned short* __restrict__ out,
                            int R, int C) {
  __shared__ float tile[32][33];
  int b = blockIdx.z;
  int r0 = blockIdx.y * 32, c0 = blockIdx.x * 32;
  int tx = threadIdx.x & 31, ty = threadIdx.x >> 5;
  const float* src = in + (size_t)b * R * C;
  unsigned short* dst = out + (size_t)b * R * C;
#pragma unroll
  for (int i = 0; i < 4; i++)
    tile[ty + i * 8][tx] = src[(size_t)(r0 + ty + i * 8) * C + c0 + tx];
  __syncthreads();
#pragma unroll
  for (int i = 0; i < 4; i++)
    dst[(size_t)(c0 + ty + i * 8) * R + r0 + tx] = f2bf(tile[tx][ty + i * 8]);
}

// ---------------- fused SwiGLU GEMM: H = silu(A@W1) * (A@W3) ----------------
// A bf16 [TTOK][DM] (gathered rows for routed), W*t bf16 [(E*)FF][DM] (B^T layout)
// BM=128 BN=64 BK=32, 4 waves (2x2), wave tile 64x32
template <bool GATHER>
__global__ __launch_bounds__(256) void k_g13(
    const unsigned short* __restrict__ xb, const unsigned short* __restrict__ W1t,
    const unsigned short* __restrict__ W3t, unsigned short* __restrict__ H,
    const int* __restrict__ slot_token, const int* __restrict__ offs,
    const int* __restrict__ counts) {
  __shared__ unsigned short As[128 * 32];
  __shared__ unsigned short Bs1[64 * 32];
  __shared__ unsigned short Bs3[64 * 32];

  int e = blockIdx.z;
  int seg = 0, cnt = TTOK;
  if (GATHER) { seg = offs[e]; cnt = counts[e]; }
  int m0 = blockIdx.y * 128;
  if (m0 >= cnt) return;
  int n0 = blockIdx.x * 64;

  int tid = threadIdx.x;
  int lane = tid & 63, wid = tid >> 6;

  // A staging: 512 chunks of 16B, 2 issues; chunk c -> row c/4, k-off (c&3)*8
  int r0 = tid >> 2, kc = tid & 3;
  long arow0, arow1;
  if (GATHER) {
    int q0 = m0 + r0;        if (q0 > cnt - 1) q0 = cnt - 1;
    int q1 = m0 + r0 + 64;   if (q1 > cnt - 1) q1 = cnt - 1;
    arow0 = slot_token[seg + q0];
    arow1 = slot_token[seg + q1];
  } else {
    arow0 = m0 + r0;
    arow1 = m0 + r0 + 64;
  }
  const unsigned short* pa0 = xb + (size_t)arow0 * DM + kc * 8;
  const unsigned short* pa1 = xb + (size_t)arow1 * DM + kc * 8;
  const unsigned short* pb1 = W1t + ((size_t)e * FF + n0 + r0) * DM + kc * 8;
  const unsigned short* pb3 = W3t + ((size_t)e * FF + n0 + r0) * DM + kc * 8;

  unsigned short* ldsA0 = As + (size_t)(wid * 64) * 8;
  unsigned short* ldsA1 = As + (size_t)(256 + wid * 64) * 8;
  unsigned short* ldsB1 = Bs1 + (size_t)(wid * 64) * 8;
  unsigned short* ldsB3 = Bs3 + (size_t)(wid * 64) * 8;

  f32x4 zero = {0.f, 0.f, 0.f, 0.f};
  f32x4 acc1[4][2], acc3[4][2];
#pragma unroll
  for (int i = 0; i < 4; i++)
#pragma unroll
    for (int j = 0; j < 2; j++) { acc1[i][j] = zero; acc3[i][j] = zero; }

  int wr = wid >> 1, wc = wid & 1;
  int kqe = (lane >> 4) * 8;  // per-lane k element offset within BK

  for (int kt = 0; kt < DM / 32; ++kt) {
    int ko = kt * 32;
    async16(pa0 + ko, ldsA0);
    async16(pa1 + ko, ldsA1);
    async16(pb1 + ko, ldsB1);
    async16(pb3 + ko, ldsB3);
    __syncthreads();
    short8 a[4], b1f[2], b3f[2];
#pragma unroll
    for (int i = 0; i < 4; i++) {
      int row = wr * 64 + i * 16 + (lane & 15);
      a[i] = *(const short8*)(As + row * 32 + kqe);
    }
#pragma unroll
    for (int j = 0; j < 2; j++) {
      int row = wc * 32 + j * 16 + (lane & 15);
      b1f[j] = *(const short8*)(Bs1 + row * 32 + kqe);
      b3f[j] = *(const short8*)(Bs3 + row * 32 + kqe);
    }
#pragma unroll
    for (int i = 0; i < 4; i++)
#pragma unroll
      for (int j = 0; j < 2; j++) {
        acc1[i][j] = __builtin_amdgcn_mfma_f32_16x16x32_bf16(a[i], b1f[j], acc1[i][j], 0, 0, 0);
        acc3[i][j] = __builtin_amdgcn_mfma_f32_16x16x32_bf16(a[i], b3f[j], acc3[i][j], 0, 0, 0);
      }
    __syncthreads();
  }

#pragma unroll
  for (int i = 0; i < 4; i++)
#pragma unroll
    for (int j = 0; j < 2; j++)
#pragma unroll
      for (int q = 0; q < 4; q++) {
        int rl = wr * 64 + i * 16 + (lane >> 4) * 4 + q;
        if (m0 + rl < cnt) {
          size_t row = GATHER ? (size_t)(seg + m0 + rl) : (size_t)(m0 + rl);
          int col = n0 + wc * 32 + j * 16 + (lane & 15);
          float s1 = acc1[i][j][q], s3 = acc3[i][j][q];
          float h = (s1 / (1.f + __expf(-s1))) * s3;
          H[row * FF + col] = f2bf(h);
        }
      }
}

// ---------------- GEMM2: out = H @ W2 ----------------
// H bf16 [rows][FF], W2t bf16 [(E*)DM][FF], out f32. BM=128 BN=128 BK=32, wave 64x64
template <bool ROUTED>
__global__ __launch_bounds__(256) void k_g2(
    const unsigned short* __restrict__ H, const unsigned short* __restrict__ W2t,
    float* __restrict__ out, const int* __restrict__ offs, const int* __restrict__ counts) {
  __shared__ unsigned short As[128 * 32];
  __shared__ unsigned short Bs[128 * 32];
  const int K = FF;

  int e = blockIdx.z;
  int seg = 0, cnt = TTOK;
  if (ROUTED) { seg = offs[e]; cnt = counts[e]; }
  int m0 = blockIdx.y * 128;
  if (m0 >= cnt) return;
  int n0 = blockIdx.x * 128;

  int tid = threadIdx.x;
  int lane = tid & 63, wid = tid >> 6;

  int r0 = tid >> 2, kc = tid & 3;
  int total = ROUTED ? 2 * TTOK : TTOK;
  long arow0 = seg + m0 + r0;       if (arow0 > total - 1) arow0 = total - 1;
  long arow1 = seg + m0 + r0 + 64;  if (arow1 > total - 1) arow1 = total - 1;
  const unsigned short* pa0 = H + (size_t)arow0 * K + kc * 8;
  const unsigned short* pa1 = H + (size_t)arow1 * K + kc * 8;
  const unsigned short* pb0 = W2t + ((size_t)e * DM + n0 + r0) * K + kc * 8;
  const unsigned short* pb1 = W2t + ((size_t)e * DM + n0 + r0 + 64) * K + kc * 8;

  unsigned short* ldsA0 = As + (size_t)(wid * 64) * 8;
  unsigned short* ldsA1 = As + (size_t)(256 + wid * 64) * 8;
  unsigned short* ldsB0 = Bs + (size_t)(wid * 64) * 8;
  unsigned short* ldsB1 = Bs + (size_t)(256 + wid * 64) * 8;

  f32x4 zero = {0.f, 0.f, 0.f, 0.f};
  f32x4 acc[4][4];
#pragma unroll
  for (int i = 0; i < 4; i++)
#pragma unroll
    for (int j = 0; j < 4; j++) acc[i][j] = zero;

  int wr = wid >> 1, wc = wid & 1;
  int kqe = (lane >> 4) * 8;

  for (int kt = 0; kt < K / 32; ++kt) {
    int ko = kt * 32;
    async16(pa0 + ko, ldsA0);
    async16(pa1 + ko, ldsA1);
    async16(pb0 + ko, ldsB0);
    async16(pb1 + ko, ldsB1);
    __syncthreads();
    short8 a[4], b[4];
#pragma unroll
    for (int i = 0; i < 4; i++) {
      int row = wr * 64 + i * 16 + (lane & 15);
      a[i] = *(const short8*)(As + row * 32 + kqe);
    }
#pragma unroll
    for (int j = 0; j < 4; j++) {
      int row = wc * 64 + j * 16 + (lane & 15);
      b[j] = *(const short8*)(Bs + row * 32 + kqe);
    }
#pragma unroll
    for (int i = 0; i < 4; i++)
#pragma unroll
      for (int j = 0; j < 4; j++)
        acc[i][j] = __builtin_amdgcn_mfma_f32_16x16x32_bf16(a[i], b[j], acc[i][j], 0, 0, 0);
    __syncthreads();
  }

#pragma unroll
  for (int i = 0; i < 4; i++)
#pragma unroll
    for (int j = 0; j < 4; j++)
#pragma unroll
      for (int q = 0; q < 4; q++) {
        int rl = wr * 64 + i * 16 + (lane >> 4) * 4 + q;
        if (m0 + rl < cnt) {
          size_t row = (size_t)(seg + m0 + rl);
          int col = n0 + wc * 64 + j * 16 + (lane & 15);
          out[row * DM + col] = acc[i][j][q];
        }
      }
}

// out[t] = (shared[t] + w0*contrib[s0] + w1*contrib[s1]) / 3
__global__ void k_combine(float* __restrict__ out, const float* __restrict__ contrib,
                          const int* __restrict__ token_slot, const float* __restrict__ topkw) {
  int t = blockIdx.x;
  int c = threadIdx.x * 4;
  int s0 = token_slot[t * 2 + 0], s1 = token_slot[t * 2 + 1];
  float w0 = topkw[t * 2 + 0], w1 = topkw[t * 2 + 1];
  float* po = out + (size_t)t * DM + c;
  const float* p0 = contrib + (size_t)s0 * DM + c;
  const float* p1 = contrib + (size_t)s1 * DM + c;
#pragma unroll
  for (int i = 0; i < 4; i++)
    po[i] = (po[i] + w0 * p0[i] + w1 * p1[i]) * (1.f / 3.f);
}

// ---------------- launcher ----------------
extern "C" void kernel_launch(void* const* d_in, const int* in_sizes, int n_in,
                              void* d_out, int out_size, void* d_ws, size_t ws_size,
                              hipStream_t stream) {
  const float* x   = (const float*)d_in[0];
  const float* Wg  = (const float*)d_in[1];
  const float* Ws1 = (const float*)d_in[2];
  const float* Ws3 = (const float*)d_in[3];
  const float* Ws2 = (const float*)d_in[4];
  const float* We1 = (const float*)d_in[5];
  const float* We3 = (const float*)d_in[6];
  const float* We2 = (const float*)d_in[7];
  float* out = (float*)d_out;

  if (ws_size < WS_NEEDED) return;  // diagnosable failure (poison stays in d_out)

  char* w = (char*)d_ws;
  unsigned short* xb   = (unsigned short*)(w + OFF_XB);
  unsigned short* ws1t = (unsigned short*)(w + OFF_WS1T);
  unsigned short* ws3t = (unsigned short*)(w + OFF_WS3T);
  unsigned short* ws2t = (unsigned short*)(w + OFF_WS2T);
  unsigned short* we1t = (unsigned short*)(w + OFF_WE1T);
  unsigned short* we3t = (unsigned short*)(w + OFF_WE3T);
  unsigned short* we2t = (unsigned short*)(w + OFF_WE2T);
  unsigned short* hsh  = (unsigned short*)(w + OFF_HSH);
  unsigned short* hrt  = (unsigned short*)(w + OFF_HRT);
  float* contrib       = (float*)(w + OFF_CONTRIB);
  float* topkw         = (float*)(w + OFF_TOPKW);
  int* topki           = (int*)(w + OFF_TOPKI);
  int* slot_token      = (int*)(w + OFF_SLOTTOK);
  int* token_slot      = (int*)(w + OFF_TOKSLOT);
  int* counts          = (int*)(w + OFF_COUNTS);
  int* fills           = counts + 8;
  int* offs            = counts + 16;

  k_zero<<<1, 64, 0, stream>>>(counts, 24);
  k_gate<<<TTOK / 4, 256, 0, stream>>>(x, Wg, topkw, topki, counts);
  k_offsets<<<1, 1, 0, stream>>>(counts, offs);
  k_fill<<<TTOK / 256, 256, 0, stream>>>(topki, offs, fills, slot_token, token_slot);
  k_cvt_x<<<TTOK * DM / 8 / 256, 256, 0, stream>>>(x, xb);
  k_transpose<<<dim3(FF / 32, DM / 32, 1), 256, 0, stream>>>(Ws1, ws1t, DM, FF);
  k_transpose<<<dim3(FF / 32, DM / 32, 1), 256, 0, stream>>>(Ws3, ws3t, DM, FF);
  k_transpose<<<dim3(DM / 32, FF / 32, 1), 256, 0, stream>>>(Ws2, ws2t, FF, DM);
  k_transpose<<<dim3(FF / 32, DM / 32, NE), 256, 0, stream>>>(We1, we1t, DM, FF);
  k_transpose<<<dim3(FF / 32, DM / 32, NE), 256, 0, stream>>>(We3, we3t, DM, FF);
  k_transpose<<<dim3(DM / 32, FF / 32, NE), 256, 0, stream>>>(We2, we2t, FF, DM);

  k_g13<false><<<dim3(FF / 64, TTOK / 128, 1), 256, 0, stream>>>(
      xb, ws1t, ws3t, hsh, nullptr, nullptr, nullptr);
  k_g13<true><<<dim3(FF / 64, TTOK / 128, NE), 256, 0, stream>>>(
      xb, we1t, we3t, hrt, slot_token, offs, counts);
  k_g2<false><<<dim3(DM / 128, TTOK / 128, 1), 256, 0, stream>>>(
      hsh, ws2t, out, nullptr, nullptr);
  k_g2<true><<<dim3(DM / 128, TTOK / 128, NE), 256, 0, stream>>>(
      hrt, we2t, contrib, offs, counts);
  k_combine<<<TTOK, 256, 0, stream>>>(out, contrib, token_slot, topkw);
}

// Round 2
// 501.460 us; speedup vs baseline: 1.1158x; 1.1158x over previous
//
#include <hip/hip_runtime.h>
#include <stdint.h>

#define TTOK 4096
#define DM   1024
#define FF   2048
#define NE   8

typedef __attribute__((ext_vector_type(8))) short short8;
typedef __attribute__((ext_vector_type(4))) float f32x4;

// ---------------- workspace layout (bytes) ----------------
#define OFF_XB      0ull
#define OFF_WB13    (OFF_XB      + (size_t)TTOK*DM*2)          // [9][4096][1024] bf16 (W1/W3 interleaved 16-row groups)
#define OFF_WB2     (OFF_WB13    + (size_t)9*4096*1024*2)      // [9][1024][2048] bf16
#define OFF_H       (OFF_WB2     + (size_t)9*1024*2048*2)      // [12288][2048] bf16 (slots 0..8191 routed, 8192+ shared)
#define OFF_CONTRIB (OFF_H       + (size_t)12288*2048*2)       // [8192][1024] f32
#define OFF_TOPKW   (OFF_CONTRIB + (size_t)8192*1024*4)
#define OFF_TOPKI   (OFF_TOPKW   + (size_t)TTOK*2*4)
#define OFF_SLOTTOK (OFF_TOPKI   + (size_t)TTOK*2*4)
#define OFF_TOKSLOT (OFF_SLOTTOK + (size_t)TTOK*2*4)
#define OFF_COUNTS  (OFF_TOKSLOT + (size_t)TTOK*2*4)
#define WS_NEEDED   (OFF_COUNTS + 256)

#define VMWAIT(N) asm volatile("s_waitcnt vmcnt(" #N ")" ::: "memory")
#define LGKM0()   asm volatile("s_waitcnt lgkmcnt(0)" ::: "memory")
#define BAR()     __builtin_amdgcn_s_barrier()
#define SCHED0()  __builtin_amdgcn_sched_barrier(0)

__device__ __forceinline__ unsigned short f2bf(float f) {
  unsigned u = __float_as_uint(f);
  return (unsigned short)((u + 0x7FFFu + ((u >> 16) & 1u)) >> 16);
}

__device__ __forceinline__ void async16(const void* g, void* l) {
  __builtin_amdgcn_global_load_lds(
      (const __attribute__((address_space(1))) void*)g,
      (__attribute__((address_space(3))) void*)l, 16, 0, 0);
}

// ---------------- small kernels ----------------
__global__ void k_zero(int* p, int n) {
  int i = threadIdx.x;
  if (i < n) p[i] = 0;
}

// one wave per token: fp32 gate logits + sigmoid top-2; also converts x -> bf16
__global__ void k_gatecvt(const float* __restrict__ x, const float* __restrict__ Wg,
                          float* __restrict__ topkw, int* __restrict__ topki,
                          int* __restrict__ counts, unsigned short* __restrict__ xb) {
  int wave = threadIdx.x >> 6;
  int lane = threadIdx.x & 63;
  int t = blockIdx.x * 4 + wave;
  float acc[NE];
#pragma unroll
  for (int e = 0; e < NE; e++) acc[e] = 0.f;
  const float* xr = x + (size_t)t * DM;
  unsigned short* xbr = xb + (size_t)t * DM;
  for (int i = 0; i < DM / 64; i++) {
    int k = lane + i * 64;
    float xv = xr[k];
    xbr[k] = f2bf(xv);
    const float* wr = Wg + (size_t)k * NE;
#pragma unroll
    for (int e = 0; e < NE; e++) acc[e] += xv * wr[e];
  }
#pragma unroll
  for (int e = 0; e < NE; e++) {
#pragma unroll
    for (int off = 32; off >= 1; off >>= 1) acc[e] += __shfl_xor(acc[e], off, 64);
  }
  if (lane == 0) {
    float g[NE];
#pragma unroll
    for (int e = 0; e < NE; e++) g[e] = 1.f / (1.f + __expf(-acc[e]));
    int i1 = -1, i2 = -1;
    float m1 = -1e30f, m2 = -1e30f;
#pragma unroll
    for (int e = 0; e < NE; e++) {
      float v = g[e];
      if (v > m1) { m2 = m1; i2 = i1; m1 = v; i1 = e; }
      else if (v > m2) { m2 = v; i2 = e; }
    }
    float s = m1 + m2;
    topkw[t * 2 + 0] = m1 / s;
    topkw[t * 2 + 1] = m2 / s;
    topki[t * 2 + 0] = i1;
    topki[t * 2 + 1] = i2;
    atomicAdd(&counts[i1], 1);
    atomicAdd(&counts[i2], 1);
  }
}

__global__ void k_offsets(const int* __restrict__ counts, int* __restrict__ offs) {
  if (threadIdx.x == 0 && blockIdx.x == 0) {
    int s = 0;
    for (int e = 0; e < NE; e++) { offs[e] = s; s += counts[e]; }
  }
}

__global__ void k_fill(const int* __restrict__ topki, const int* __restrict__ offs,
                       int* __restrict__ fills, int* __restrict__ slot_token,
                       int* __restrict__ token_slot) {
  int t = blockIdx.x * 256 + threadIdx.x;
  if (t >= TTOK) return;
#pragma unroll
  for (int k = 0; k < 2; k++) {
    int e = topki[t * 2 + k];
    int pos = atomicAdd(&fills[e], 1);
    int slot = offs[e] + pos;
    slot_token[slot] = t;
    token_slot[t * 2 + k] = slot;
  }
}

// W1/W3 [DM][FF] f32 -> wb13 [z][4096][1024] bf16, W1 col n -> row (n>>4)*32+(n&15), W3 -> +16
__global__ void k_t13(const float* __restrict__ We1, const float* __restrict__ We3,
                      const float* __restrict__ Ws1, const float* __restrict__ Ws3,
                      unsigned short* __restrict__ wb13) {
  __shared__ float tile[32][33];
  int z = blockIdx.z;
  const float* w1 = (z < 8) ? We1 + (size_t)z * DM * FF : Ws1;
  const float* w3 = (z < 8) ? We3 + (size_t)z * DM * FF : Ws3;
  unsigned short* dst = wb13 + (size_t)z * 4096 * 1024;
  int r0 = blockIdx.y * 32, c0 = blockIdx.x * 32;   // r0: k (DM), c0: n (FF)
  int tx = threadIdx.x & 31, ty = threadIdx.x >> 5;
#pragma unroll
  for (int i = 0; i < 4; i++)
    tile[ty + i * 8][tx] = w1[(size_t)(r0 + ty + i * 8) * FF + c0 + tx];
  __syncthreads();
#pragma unroll
  for (int i = 0; i < 4; i++) {
    int n = c0 + ty + i * 8;
    int d = ((n >> 4) << 5) + (n & 15);
    dst[(size_t)d * 1024 + r0 + tx] = f2bf(tile[tx][ty + i * 8]);
  }
  __syncthreads();
#pragma unroll
  for (int i = 0; i < 4; i++)
    tile[ty + i * 8][tx] = w3[(size_t)(r0 + ty + i * 8) * FF + c0 + tx];
  __syncthreads();
#pragma unroll
  for (int i = 0; i < 4; i++) {
    int n = c0 + ty + i * 8;
    int d = ((n >> 4) << 5) + 16 + (n & 15);
    dst[(size_t)d * 1024 + r0 + tx] = f2bf(tile[tx][ty + i * 8]);
  }
}

// W2 [FF][DM] f32 -> wb2 [z][1024][2048] bf16 (plain transpose)
__global__ void k_t2(const float* __restrict__ We2, const float* __restrict__ Ws2,
                     unsigned short* __restrict__ wb2) {
  __shared__ float tile[32][33];
  int z = blockIdx.z;
  const float* w2 = (z < 8) ? We2 + (size_t)z * FF * DM : Ws2;
  unsigned short* dst = wb2 + (size_t)z * 1024 * 2048;
  int r0 = blockIdx.y * 32, c0 = blockIdx.x * 32;   // r0: k (FF), c0: n (DM)
  int tx = threadIdx.x & 31, ty = threadIdx.x >> 5;
#pragma unroll
  for (int i = 0; i < 4; i++)
    tile[ty + i * 8][tx] = w2[(size_t)(r0 + ty + i * 8) * DM + c0 + tx];
  __syncthreads();
#pragma unroll
  for (int i = 0; i < 4; i++)
    dst[(size_t)(c0 + ty + i * 8) * 2048 + r0 + tx] = f2bf(tile[tx][ty + i * 8]);
}

// ---------------- grouped 256x256 GEMM, BK=64, 8 waves, counted-vmcnt 4-phase ----------------
// G13: A=xb gathered rows (K=1024), B=wb13 (NBROW=4096), SwiGLU epilogue -> H bf16
// !G13: A=H rows (K=2048), B=wb2 (NBROW=1024), f32 epilogue -> contrib / out
template <bool G13, int K, int NBROW>
__global__ __launch_bounds__(512, 2) void k_gemm(
    const unsigned short* __restrict__ A, const unsigned short* __restrict__ B,
    unsigned short* __restrict__ Hout, float* __restrict__ Cout, float* __restrict__ Dout,
    const int* __restrict__ slot_token, const int* __restrict__ offs,
    const int* __restrict__ counts) {
  __shared__ unsigned short lds[2][2][16384];   // [dbuf][A|B][256*64] = 128 KiB
  const int NT = K / 64;

  int e = blockIdx.z;
  int seg, cnt;
  if (e == 8) { seg = 8192; cnt = 4096; }
  else        { seg = offs[e]; cnt = counts[e]; }
  int m0 = blockIdx.y * 256;
  if (m0 >= cnt) return;
  int bn = blockIdx.x;

  int tid = threadIdx.x, lane = tid & 63, w = tid >> 6;

  // staging: chunk c = L*512 + w*64 + lane -> LDS row c>>3, slot c&7; source slot = slot^(row&7)
  int slb = (((lane & 7) ^ (lane >> 3)) << 4);   // source byte offset within 128B row
  const char* asrc[4];
  const char* bsrc[4];
#pragma unroll
  for (int L = 0; L < 4; L++) {
    int row = L * 64 + w * 8 + (lane >> 3);
    int r = m0 + row; if (r > cnt - 1) r = cnt - 1;
    long tok;
    if (G13) tok = (e == 8) ? (long)r : (long)slot_token[seg + r];
    else     tok = (long)(seg + r);
    asrc[L] = (const char*)A + ((size_t)tok * K) * 2 + slb;
    int br = bn * 256 + row;
    bsrc[L] = (const char*)B + (((size_t)e * NBROW + br) * K) * 2 + slb;
  }

#define STAGE(b, kt) do {                                        \
    unsigned short* _la = &lds[b][0][(w * 64) * 8];              \
    unsigned short* _lb = &lds[b][1][(w * 64) * 8];              \
    _Pragma("unroll")                                            \
    for (int L = 0; L < 4; L++) {                                \
      async16(asrc[L] + (size_t)(kt) * 128, _la + L * 4096);     \
      async16(bsrc[L] + (size_t)(kt) * 128, _lb + L * 4096);     \
    }                                                            \
  } while (0)

  // fragment read bases (bytes)
  int wr = w >> 2, wc = w & 3;
  int rbA = (wr * 128 + (lane & 15)) * 128;
  int rbB = (wc * 64 + (lane & 15)) * 128;
  int sb0 = ((((lane >> 4) + 0) ^ (lane & 7)) << 4);
  int sb1 = ((((lane >> 4) + 4) ^ (lane & 7)) << 4);

  f32x4 acc[8][4];
#pragma unroll
  for (int i = 0; i < 8; i++)
#pragma unroll
    for (int j = 0; j < 4; j++) acc[i][j] = (f32x4){0.f, 0.f, 0.f, 0.f};

  STAGE(0, 0);
  STAGE(1, 1);
  VMWAIT(8);
  BAR();

  for (int t = 0; t < NT; ++t) {
    const char* LA = (const char*)&lds[t & 1][0][0];
    const char* LB = (const char*)&lds[t & 1][1][0];
    short8 Af[4], Bf[4];

    // phase 1: ks0, m0-3 (4 B + 4 A reads, 16 MFMA)
#pragma unroll
    for (int nf = 0; nf < 4; nf++) Bf[nf] = *(const short8*)(LB + rbB + nf * 2048 + sb0);
#pragma unroll
    for (int mi = 0; mi < 4; mi++) Af[mi] = *(const short8*)(LA + rbA + mi * 2048 + sb0);
    BAR(); LGKM0(); SCHED0();
    __builtin_amdgcn_s_setprio(1);
#pragma unroll
    for (int mi = 0; mi < 4; mi++)
#pragma unroll
      for (int nf = 0; nf < 4; nf++)
        acc[mi][nf] = __builtin_amdgcn_mfma_f32_16x16x32_bf16(Af[mi], Bf[nf], acc[mi][nf], 0, 0, 0);
    __builtin_amdgcn_s_setprio(0);
    BAR();

    // phase 2: ks0, m4-7 (4 A reads)
#pragma unroll
    for (int mi = 0; mi < 4; mi++) Af[mi] = *(const short8*)(LA + rbA + (mi + 4) * 2048 + sb0);
    BAR(); LGKM0(); SCHED0();
    __builtin_amdgcn_s_setprio(1);
#pragma unroll
    for (int mi = 0; mi < 4; mi++)
#pragma unroll
      for (int nf = 0; nf < 4; nf++)
        acc[mi + 4][nf] = __builtin_amdgcn_mfma_f32_16x16x32_bf16(Af[mi], Bf[nf], acc[mi + 4][nf], 0, 0, 0);
    __builtin_amdgcn_s_setprio(0);
    BAR();

    // phase 3: ks1, m0-3 (4 B + 4 A reads)
#pragma unroll
    for (int nf = 0; nf < 4; nf++) Bf[nf] = *(const short8*)(LB + rbB + nf * 2048 + sb1);
#pragma unroll
    for (int mi = 0; mi < 4; mi++) Af[mi] = *(const short8*)(LA + rbA + mi * 2048 + sb1);
    BAR(); LGKM0(); SCHED0();
    __builtin_amdgcn_s_setprio(1);
#pragma unroll
    for (int mi = 0; mi < 4; mi++)
#pragma unroll
      for (int nf = 0; nf < 4; nf++)
        acc[mi][nf] = __builtin_amdgcn_mfma_f32_16x16x32_bf16(Af[mi], Bf[nf], acc[mi][nf], 0, 0, 0);
    __builtin_amdgcn_s_setprio(0);
    BAR();

    // phase 4: ks1, m4-7 (4 A reads)
#pragma unroll
    for (int mi = 0; mi < 4; mi++) Af[mi] = *(const short8*)(LA + rbA + (mi + 4) * 2048 + sb1);
    BAR(); LGKM0(); SCHED0();
    __builtin_amdgcn_s_setprio(1);
#pragma unroll
    for (int mi = 0; mi < 4; mi++)
#pragma unroll
      for (int nf = 0; nf < 4; nf++)
        acc[mi + 4][nf] = __builtin_amdgcn_mfma_f32_16x16x32_bf16(Af[mi], Bf[nf], acc[mi + 4][nf], 0, 0, 0);
    __builtin_amdgcn_s_setprio(0);
    BAR();

    // tile boundary: stage t+2 into the buffer we just finished reading; counted wait
    if (t + 2 < NT) {
      STAGE(t & 1, t + 2);
      VMWAIT(8);          // tile t+1 landed; tile t+2's 8 loads stay in flight
      BAR();
    } else if (t == NT - 2) {
      VMWAIT(0);          // tail: last tile landed (had a full tile of compute to cover)
      BAR();
    }
  }
#undef STAGE

  // ---------------- epilogue ----------------
  if (G13) {
#pragma unroll
    for (int mi = 0; mi < 8; mi++)
#pragma unroll
      for (int j = 0; j < 2; j++)
#pragma unroll
        for (int q = 0; q < 4; q++) {
          int rl = wr * 128 + mi * 16 + (lane >> 4) * 4 + q;
          if (m0 + rl < cnt) {
            float s1 = acc[mi][2 * j][q], s3 = acc[mi][2 * j + 1][q];
            float h = (s1 / (1.f + __expf(-s1))) * s3;
            int col = bn * 128 + wc * 32 + j * 16 + (lane & 15);
            Hout[(size_t)(seg + m0 + rl) * 2048 + col] = f2bf(h);
          }
        }
  } else {
#pragma unroll
    for (int mi = 0; mi < 8; mi++)
#pragma unroll
      for (int nf = 0; nf < 4; nf++)
#pragma unroll
        for (int q = 0; q < 4; q++) {
          int rl = wr * 128 + mi * 16 + (lane >> 4) * 4 + q;
          if (m0 + rl < cnt) {
            int col = bn * 256 + wc * 64 + nf * 16 + (lane & 15);
            if (e == 8) Dout[(size_t)(m0 + rl) * 1024 + col] = acc[mi][nf][q];
            else        Cout[(size_t)(seg + m0 + rl) * 1024 + col] = acc[mi][nf][q];
          }
        }
  }
}

// out[t] = (shared[t] + w0*contrib[s0] + w1*contrib[s1]) / 3   (shared already in out)
__global__ void k_combine(float* __restrict__ out, const float* __restrict__ contrib,
                          const int* __restrict__ token_slot, const float* __restrict__ topkw) {
  int t = blockIdx.x;
  int c = threadIdx.x * 4;
  int s0 = token_slot[t * 2 + 0], s1 = token_slot[t * 2 + 1];
  float w0 = topkw[t * 2 + 0], w1 = topkw[t * 2 + 1];
  float* po = out + (size_t)t * DM + c;
  const float* p0 = contrib + (size_t)s0 * DM + c;
  const float* p1 = contrib + (size_t)s1 * DM + c;
#pragma unroll
  for (int i = 0; i < 4; i++)
    po[i] = (po[i] + w0 * p0[i] + w1 * p1[i]) * (1.f / 3.f);
}

// ---------------- launcher ----------------
extern "C" void kernel_launch(void* const* d_in, const int* in_sizes, int n_in,
                              void* d_out, int out_size, void* d_ws, size_t ws_size,
                              hipStream_t stream) {
  const float* x   = (const float*)d_in[0];
  const float* Wg  = (const float*)d_in[1];
  const float* Ws1 = (const float*)d_in[2];
  const float* Ws3 = (const float*)d_in[3];
  const float* Ws2 = (const float*)d_in[4];
  const float* We1 = (const float*)d_in[5];
  const float* We3 = (const float*)d_in[6];
  const float* We2 = (const float*)d_in[7];
  float* out = (float*)d_out;

  if (ws_size < WS_NEEDED) return;

  char* w = (char*)d_ws;
  unsigned short* xb   = (unsigned short*)(w + OFF_XB);
  unsigned short* wb13 = (unsigned short*)(w + OFF_WB13);
  unsigned short* wb2  = (unsigned short*)(w + OFF_WB2);
  unsigned short* H    = (unsigned short*)(w + OFF_H);
  float* contrib       = (float*)(w + OFF_CONTRIB);
  float* topkw         = (float*)(w + OFF_TOPKW);
  int* topki           = (int*)(w + OFF_TOPKI);
  int* slot_token      = (int*)(w + OFF_SLOTTOK);
  int* token_slot      = (int*)(w + OFF_TOKSLOT);
  int* counts          = (int*)(w + OFF_COUNTS);
  int* fills           = counts + 8;
  int* offs            = counts + 16;

  k_zero<<<1, 64, 0, stream>>>(counts, 16);
  k_gatecvt<<<TTOK / 4, 256, 0, stream>>>(x, Wg, topkw, topki, counts, xb);
  k_offsets<<<1, 1, 0, stream>>>(counts, offs);
  k_fill<<<TTOK / 256, 256, 0, stream>>>(topki, offs, fills, slot_token, token_slot);
  k_t13<<<dim3(FF / 32, DM / 32, 9), 256, 0, stream>>>(We1, We3, Ws1, Ws3, wb13);
  k_t2<<<dim3(DM / 32, FF / 32, 9), 256, 0, stream>>>(We2, Ws2, wb2);

  k_gemm<true, 1024, 4096><<<dim3(16, 16, 9), 512, 0, stream>>>(
      xb, wb13, H, nullptr, nullptr, slot_token, offs, counts);
  k_gemm<false, 2048, 1024><<<dim3(4, 16, 9), 512, 0, stream>>>(
      H, wb2, nullptr, contrib, out, slot_token, offs, counts);

  k_combine<<<TTOK, 256, 0, stream>>>(out, contrib, token_slot, topkw);
}

// Round 3
// 477.223 us; speedup vs baseline: 1.1725x; 1.0508x over previous
//
#include <hip/hip_runtime.h>
#include <stdint.h>

#define TTOK 4096
#define DM   1024
#define FF   2048
#define NE   8

typedef __attribute__((ext_vector_type(8))) short short8;
typedef __attribute__((ext_vector_type(4))) float f32x4;

// ---------------- workspace layout (bytes) ----------------
#define OFF_XB      0ull
#define OFF_WB13    (OFF_XB      + (size_t)TTOK*DM*2)          // [9][4096][1024] bf16 (W1/W3 interleaved 16-row groups)
#define OFF_WB2     (OFF_WB13    + (size_t)9*4096*1024*2)      // [9][1024][2048] bf16
#define OFF_H       (OFF_WB2     + (size_t)9*1024*2048*2)      // [12288][2048] bf16 (slots 0..8191 routed, 8192+ shared)
#define OFF_CONTRIB (OFF_H       + (size_t)12288*2048*2)       // [8192][1024] f32
#define OFF_TOPKW   (OFF_CONTRIB + (size_t)8192*1024*4)
#define OFF_TOPKI   (OFF_TOPKW   + (size_t)TTOK*2*4)
#define OFF_SLOTTOK (OFF_TOPKI   + (size_t)TTOK*2*4)
#define OFF_TOKSLOT (OFF_SLOTTOK + (size_t)TTOK*2*4)
#define OFF_COUNTS  (OFF_TOKSLOT + (size_t)TTOK*2*4)
#define WS_NEEDED   (OFF_COUNTS + 256)

__device__ __forceinline__ unsigned short f2bf(float f) {
  unsigned u = __float_as_uint(f);
  return (unsigned short)((u + 0x7FFFu + ((u >> 16) & 1u)) >> 16);
}

__device__ __forceinline__ void async16(const void* g, void* l) {
  __builtin_amdgcn_global_load_lds(
      (const __attribute__((address_space(1))) void*)g,
      (__attribute__((address_space(3))) void*)l, 16, 0, 0);
}

// ---------------- small kernels ----------------
__global__ void k_zero(int* p, int n) {
  int i = threadIdx.x;
  if (i < n) p[i] = 0;
}

// one wave per token: fp32 gate logits + sigmoid top-2; also converts x -> bf16
__global__ void k_gatecvt(const float* __restrict__ x, const float* __restrict__ Wg,
                          float* __restrict__ topkw, int* __restrict__ topki,
                          int* __restrict__ counts, unsigned short* __restrict__ xb) {
  int wave = threadIdx.x >> 6;
  int lane = threadIdx.x & 63;
  int t = blockIdx.x * 4 + wave;
  float acc[NE];
#pragma unroll
  for (int e = 0; e < NE; e++) acc[e] = 0.f;
  const float* xr = x + (size_t)t * DM;
  unsigned short* xbr = xb + (size_t)t * DM;
  for (int i = 0; i < DM / 64; i++) {
    int k = lane + i * 64;
    float xv = xr[k];
    xbr[k] = f2bf(xv);
    const float* wr = Wg + (size_t)k * NE;
#pragma unroll
    for (int e = 0; e < NE; e++) acc[e] += xv * wr[e];
  }
#pragma unroll
  for (int e = 0; e < NE; e++) {
#pragma unroll
    for (int off = 32; off >= 1; off >>= 1) acc[e] += __shfl_xor(acc[e], off, 64);
  }
  if (lane == 0) {
    float g[NE];
#pragma unroll
    for (int e = 0; e < NE; e++) g[e] = 1.f / (1.f + __expf(-acc[e]));
    int i1 = -1, i2 = -1;
    float m1 = -1e30f, m2 = -1e30f;
#pragma unroll
    for (int e = 0; e < NE; e++) {
      float v = g[e];
      if (v > m1) { m2 = m1; i2 = i1; m1 = v; i1 = e; }
      else if (v > m2) { m2 = v; i2 = e; }
    }
    float s = m1 + m2;
    topkw[t * 2 + 0] = m1 / s;
    topkw[t * 2 + 1] = m2 / s;
    topki[t * 2 + 0] = i1;
    topki[t * 2 + 1] = i2;
    atomicAdd(&counts[i1], 1);
    atomicAdd(&counts[i2], 1);
  }
}

__global__ void k_offsets(const int* __restrict__ counts, int* __restrict__ offs) {
  if (threadIdx.x == 0 && blockIdx.x == 0) {
    int s = 0;
    for (int e = 0; e < NE; e++) { offs[e] = s; s += counts[e]; }
  }
}

__global__ void k_fill(const int* __restrict__ topki, const int* __restrict__ offs,
                       int* __restrict__ fills, int* __restrict__ slot_token,
                       int* __restrict__ token_slot) {
  int t = blockIdx.x * 256 + threadIdx.x;
  if (t >= TTOK) return;
#pragma unroll
  for (int k = 0; k < 2; k++) {
    int e = topki[t * 2 + k];
    int pos = atomicAdd(&fills[e], 1);
    int slot = offs[e] + pos;
    slot_token[slot] = t;
    token_slot[t * 2 + k] = slot;
  }
}

// W1/W3 [DM][FF] f32 -> wb13 [z][4096][1024] bf16, W1 col n -> row (n>>4)*32+(n&15), W3 -> +16
__global__ void k_t13(const float* __restrict__ We1, const float* __restrict__ We3,
                      const float* __restrict__ Ws1, const float* __restrict__ Ws3,
                      unsigned short* __restrict__ wb13) {
  __shared__ float tile[32][33];
  int z = blockIdx.z;
  const float* w1 = (z < 8) ? We1 + (size_t)z * DM * FF : Ws1;
  const float* w3 = (z < 8) ? We3 + (size_t)z * DM * FF : Ws3;
  unsigned short* dst = wb13 + (size_t)z * 4096 * 1024;
  int r0 = blockIdx.y * 32, c0 = blockIdx.x * 32;   // r0: k (DM), c0: n (FF)
  int tx = threadIdx.x & 31, ty = threadIdx.x >> 5;
#pragma unroll
  for (int i = 0; i < 4; i++)
    tile[ty + i * 8][tx] = w1[(size_t)(r0 + ty + i * 8) * FF + c0 + tx];
  __syncthreads();
#pragma unroll
  for (int i = 0; i < 4; i++) {
    int n = c0 + ty + i * 8;
    int d = ((n >> 4) << 5) + (n & 15);
    dst[(size_t)d * 1024 + r0 + tx] = f2bf(tile[tx][ty + i * 8]);
  }
  __syncthreads();
#pragma unroll
  for (int i = 0; i < 4; i++)
    tile[ty + i * 8][tx] = w3[(size_t)(r0 + ty + i * 8) * FF + c0 + tx];
  __syncthreads();
#pragma unroll
  for (int i = 0; i < 4; i++) {
    int n = c0 + ty + i * 8;
    int d = ((n >> 4) << 5) + 16 + (n & 15);
    dst[(size_t)d * 1024 + r0 + tx] = f2bf(tile[tx][ty + i * 8]);
  }
}

// W2 [FF][DM] f32 -> wb2 [z][1024][2048] bf16 (plain transpose)
__global__ void k_t2(const float* __restrict__ We2, const float* __restrict__ Ws2,
                     unsigned short* __restrict__ wb2) {
  __shared__ float tile[32][33];
  int z = blockIdx.z;
  const float* w2 = (z < 8) ? We2 + (size_t)z * FF * DM : Ws2;
  unsigned short* dst = wb2 + (size_t)z * 1024 * 2048;
  int r0 = blockIdx.y * 32, c0 = blockIdx.x * 32;   // r0: k (FF), c0: n (DM)
  int tx = threadIdx.x & 31, ty = threadIdx.x >> 5;
#pragma unroll
  for (int i = 0; i < 4; i++)
    tile[ty + i * 8][tx] = w2[(size_t)(r0 + ty + i * 8) * DM + c0 + tx];
  __syncthreads();
#pragma unroll
  for (int i = 0; i < 4; i++)
    dst[(size_t)(c0 + ty + i * 8) * 2048 + r0 + tx] = f2bf(tile[tx][ty + i * 8]);
}

// ---------------- m97-style 128x128 GEMM, BK=64, 4 waves, single-buffer LDS ----------------
// G13: A=xb gathered rows (K=1024), B=wb13 (NBROW=4096), SwiGLU epilogue -> H bf16
// !G13: A=H rows (K=2048), B=wb2 (NBROW=1024), f32 epilogue -> contrib / out
template <bool G13, int K, int NBROW>
__global__ __launch_bounds__(256) void k_gemm(
    const unsigned short* __restrict__ A, const unsigned short* __restrict__ B,
    unsigned short* __restrict__ Hout, float* __restrict__ Cout, float* __restrict__ Dout,
    const int* __restrict__ slot_token, const int* __restrict__ offs,
    const int* __restrict__ counts) {
  __shared__ unsigned short As[128 * 64];   // 16 KiB, rows of 128B = 8 slots of 16B (XOR-swizzled)
  __shared__ unsigned short Bs[128 * 64];
  const int NT = K / 64;

  int e = blockIdx.z;
  int seg, cnt;
  if (e == 8) { seg = 8192; cnt = 4096; }
  else        { seg = offs[e]; cnt = counts[e]; }
  int m0 = blockIdx.y * 128;
  if (m0 >= cnt) return;
  int bn = blockIdx.x;

  int tid = threadIdx.x, lane = tid & 63, w = tid >> 6;

  // staging: issue L covers rows L*32 + w*8 + (lane>>3); LDS slot lane&7, src slot = (lane&7)^(row&7)
  int slb = (((lane & 7) ^ (lane >> 3)) << 4);   // source byte offset within 128B row
  const char* asrc[4];
  const char* bsrc[4];
#pragma unroll
  for (int L = 0; L < 4; L++) {
    int row = L * 32 + w * 8 + (lane >> 3);
    int r = m0 + row; if (r > cnt - 1) r = cnt - 1;
    long tok;
    if (G13) tok = (e == 8) ? (long)r : (long)slot_token[seg + r];
    else     tok = (long)(seg + r);
    asrc[L] = (const char*)A + ((size_t)tok * K) * 2 + slb;
    int br = bn * 128 + row;
    bsrc[L] = (const char*)B + (((size_t)e * NBROW + br) * K) * 2 + slb;
  }

  // fragment read bases (bytes): wave (wr,wc) owns 64x64: rows wr*64+, cols wc*64+
  int wr = w >> 1, wc = w & 1;
  int rbA = (wr * 64 + (lane & 15)) * 128;
  int rbB = (wc * 64 + (lane & 15)) * 128;
  int sb0 = ((((lane >> 4) + 0) ^ (lane & 7)) << 4);
  int sb1 = ((((lane >> 4) + 4) ^ (lane & 7)) << 4);

  f32x4 acc[4][4];
#pragma unroll
  for (int i = 0; i < 4; i++)
#pragma unroll
    for (int j = 0; j < 4; j++) acc[i][j] = (f32x4){0.f, 0.f, 0.f, 0.f};

  for (int kt = 0; kt < NT; ++kt) {
    // stage this K-tile (A: 4 issues, B: 4 issues; each 1KiB/wave)
#pragma unroll
    for (int L = 0; L < 4; L++) {
      async16(asrc[L] + (size_t)kt * 128, As + L * 2048 + w * 512);
      async16(bsrc[L] + (size_t)kt * 128, Bs + L * 2048 + w * 512);
    }
    __syncthreads();   // drains vmcnt(0): staged data visible

    short8 Af[4], Bf[4];
    // ks0
#pragma unroll
    for (int mi = 0; mi < 4; mi++) Af[mi] = *(const short8*)((const char*)As + rbA + mi * 2048 + sb0);
#pragma unroll
    for (int nf = 0; nf < 4; nf++) Bf[nf] = *(const short8*)((const char*)Bs + rbB + nf * 2048 + sb0);
#pragma unroll
    for (int mi = 0; mi < 4; mi++)
#pragma unroll
      for (int nf = 0; nf < 4; nf++)
        acc[mi][nf] = __builtin_amdgcn_mfma_f32_16x16x32_bf16(Af[mi], Bf[nf], acc[mi][nf], 0, 0, 0);
    // ks1
#pragma unroll
    for (int mi = 0; mi < 4; mi++) Af[mi] = *(const short8*)((const char*)As + rbA + mi * 2048 + sb1);
#pragma unroll
    for (int nf = 0; nf < 4; nf++) Bf[nf] = *(const short8*)((const char*)Bs + rbB + nf * 2048 + sb1);
#pragma unroll
    for (int mi = 0; mi < 4; mi++)
#pragma unroll
      for (int nf = 0; nf < 4; nf++)
        acc[mi][nf] = __builtin_amdgcn_mfma_f32_16x16x32_bf16(Af[mi], Bf[nf], acc[mi][nf], 0, 0, 0);
    __syncthreads();   // all reads retired before next stage overwrites
  }

  // ---------------- epilogue ----------------
  if (G13) {
#pragma unroll
    for (int mi = 0; mi < 4; mi++)
#pragma unroll
      for (int j = 0; j < 2; j++)
#pragma unroll
        for (int q = 0; q < 4; q++) {
          int rl = wr * 64 + mi * 16 + (lane >> 4) * 4 + q;
          if (m0 + rl < cnt) {
            float s1 = acc[mi][2 * j][q], s3 = acc[mi][2 * j + 1][q];
            float h = (s1 / (1.f + __expf(-s1))) * s3;
            int nrow = bn * 128 + wc * 64 + 2 * j * 16 + (lane & 15);  // W1 row in wb13 N-space
            int ffcol = ((nrow >> 5) << 4) + (nrow & 15);
            Hout[(size_t)(seg + m0 + rl) * 2048 + ffcol] = f2bf(h);
          }
        }
  } else {
#pragma unroll
    for (int mi = 0; mi < 4; mi++)
#pragma unroll
      for (int nf = 0; nf < 4; nf++)
#pragma unroll
        for (int q = 0; q < 4; q++) {
          int rl = wr * 64 + mi * 16 + (lane >> 4) * 4 + q;
          if (m0 + rl < cnt) {
            int col = bn * 128 + wc * 64 + nf * 16 + (lane & 15);
            if (e == 8) Dout[(size_t)(m0 + rl) * 1024 + col] = acc[mi][nf][q];
            else        Cout[(size_t)(seg + m0 + rl) * 1024 + col] = acc[mi][nf][q];
          }
        }
  }
}

// out[t] = (shared[t] + w0*contrib[s0] + w1*contrib[s1]) / 3   (shared already in out)
__global__ void k_combine(float* __restrict__ out, const float* __restrict__ contrib,
                          const int* __restrict__ token_slot, const float* __restrict__ topkw) {
  int t = blockIdx.x;
  int c = threadIdx.x * 4;
  int s0 = token_slot[t * 2 + 0], s1 = token_slot[t * 2 + 1];
  float w0 = topkw[t * 2 + 0], w1 = topkw[t * 2 + 1];
  float* po = out + (size_t)t * DM + c;
  const float* p0 = contrib + (size_t)s0 * DM + c;
  const float* p1 = contrib + (size_t)s1 * DM + c;
#pragma unroll
  for (int i = 0; i < 4; i++)
    po[i] = (po[i] + w0 * p0[i] + w1 * p1[i]) * (1.f / 3.f);
}

// ---------------- launcher ----------------
extern "C" void kernel_launch(void* const* d_in, const int* in_sizes, int n_in,
                              void* d_out, int out_size, void* d_ws, size_t ws_size,
                              hipStream_t stream) {
  const float* x   = (const float*)d_in[0];
  const float* Wg  = (const float*)d_in[1];
  const float* Ws1 = (const float*)d_in[2];
  const float* Ws3 = (const float*)d_in[3];
  const float* Ws2 = (const float*)d_in[4];
  const float* We1 = (const float*)d_in[5];
  const float* We3 = (const float*)d_in[6];
  const float* We2 = (const float*)d_in[7];
  float* out = (float*)d_out;

  if (ws_size < WS_NEEDED) return;

  char* w = (char*)d_ws;
  unsigned short* xb   = (unsigned short*)(w + OFF_XB);
  unsigned short* wb13 = (unsigned short*)(w + OFF_WB13);
  unsigned short* wb2  = (unsigned short*)(w + OFF_WB2);
  unsigned short* H    = (unsigned short*)(w + OFF_H);
  float* contrib       = (float*)(w + OFF_CONTRIB);
  float* topkw         = (float*)(w + OFF_TOPKW);
  int* topki           = (int*)(w + OFF_TOPKI);
  int* slot_token      = (int*)(w + OFF_SLOTTOK);
  int* token_slot      = (int*)(w + OFF_TOKSLOT);
  int* counts          = (int*)(w + OFF_COUNTS);
  int* fills           = counts + 8;
  int* offs            = counts + 16;

  k_zero<<<1, 64, 0, stream>>>(counts, 16);
  k_gatecvt<<<TTOK / 4, 256, 0, stream>>>(x, Wg, topkw, topki, counts, xb);
  k_offsets<<<1, 1, 0, stream>>>(counts, offs);
  k_fill<<<TTOK / 256, 256, 0, stream>>>(topki, offs, fills, slot_token, token_slot);
  k_t13<<<dim3(FF / 32, DM / 32, 9), 256, 0, stream>>>(We1, We3, Ws1, Ws3, wb13);
  k_t2<<<dim3(DM / 32, FF / 32, 9), 256, 0, stream>>>(We2, Ws2, wb2);

  k_gemm<true, 1024, 4096><<<dim3(32, 32, 9), 256, 0, stream>>>(
      xb, wb13, H, nullptr, nullptr, slot_token, offs, counts);
  k_gemm<false, 2048, 1024><<<dim3(8, 32, 9), 256, 0, stream>>>(
      H, wb2, nullptr, contrib, out, slot_token, offs, counts);

  k_combine<<<TTOK, 256, 0, stream>>>(out, contrib, token_slot, topkw);
}

// Round 4
// 325.656 us; speedup vs baseline: 1.7182x; 1.4654x over previous
//
#include <hip/hip_runtime.h>
#include <stdint.h>

#define TTOK 4096
#define DM   1024
#define FF   2048
#define NE   8

typedef __attribute__((ext_vector_type(8))) short short8;
typedef __attribute__((ext_vector_type(8))) unsigned short ushort8;
typedef __attribute__((ext_vector_type(4))) float f32x4;

// ---------------- workspace layout (bytes) ----------------
#define OFF_XB      0ull
#define OFF_WB13    (OFF_XB      + (size_t)TTOK*DM*2)          // [9][4096][1024] bf16 (W1/W3 interleaved 16-row groups)
#define OFF_WB2     (OFF_WB13    + (size_t)9*4096*1024*2)      // [9][1024][2048] bf16
#define OFF_H       (OFF_WB2     + (size_t)9*1024*2048*2)      // [12288][2048] bf16 (slots 0..8191 routed, 8192+ shared)
#define OFF_CONTRIB (OFF_H       + (size_t)12288*2048*2)       // [8192][1024] f32
#define OFF_TOPKW   (OFF_CONTRIB + (size_t)8192*1024*4)
#define OFF_TOPKI   (OFF_TOPKW   + (size_t)TTOK*2*4)
#define OFF_SLOTTOK (OFF_TOPKI   + (size_t)TTOK*2*4)
#define OFF_TOKSLOT (OFF_SLOTTOK + (size_t)TTOK*2*4)
#define OFF_COUNTS  (OFF_TOKSLOT + (size_t)TTOK*2*4)
#define WS_NEEDED   (OFF_COUNTS + 256)

#define VMWAIT0() asm volatile("s_waitcnt vmcnt(0)" ::: "memory")
#define BAR()     __builtin_amdgcn_s_barrier()

__device__ __forceinline__ unsigned short f2bf(float f) {
  unsigned u = __float_as_uint(f);
  return (unsigned short)((u + 0x7FFFu + ((u >> 16) & 1u)) >> 16);
}

__device__ __forceinline__ void async16(const void* g, void* l) {
  __builtin_amdgcn_global_load_lds(
      (const __attribute__((address_space(1))) void*)g,
      (__attribute__((address_space(3))) void*)l, 16, 0, 0);
}

// ---------------- gate (fp32) + x->bf16 convert, vectorized ----------------
__global__ void k_gatecvt(const float* __restrict__ x, const float* __restrict__ Wg,
                          float* __restrict__ topkw, int* __restrict__ topki,
                          unsigned short* __restrict__ xb) {
  int wave = threadIdx.x >> 6;
  int lane = threadIdx.x & 63;
  int t = blockIdx.x * 4 + wave;
  float acc[NE];
#pragma unroll
  for (int e = 0; e < NE; e++) acc[e] = 0.f;
  const float* xr = x + (size_t)t * DM;
  unsigned short* xbr = xb + (size_t)t * DM;
#pragma unroll
  for (int i = 0; i < 4; i++) {
    int k = i * 256 + lane * 4;
    f32x4 xv = *(const f32x4*)(xr + k);
    unsigned short o0 = f2bf(xv[0]), o1 = f2bf(xv[1]), o2 = f2bf(xv[2]), o3 = f2bf(xv[3]);
    unsigned long long pk = (unsigned long long)o0 | ((unsigned long long)o1 << 16) |
                            ((unsigned long long)o2 << 32) | ((unsigned long long)o3 << 48);
    *(unsigned long long*)(xbr + k) = pk;
#pragma unroll
    for (int j = 0; j < 4; j++) {
      const float* wr = Wg + (size_t)(k + j) * NE;
#pragma unroll
      for (int e = 0; e < NE; e++) acc[e] += xv[j] * wr[e];
    }
  }
#pragma unroll
  for (int e = 0; e < NE; e++) {
#pragma unroll
    for (int off = 32; off >= 1; off >>= 1) acc[e] += __shfl_xor(acc[e], off, 64);
  }
  if (lane == 0) {
    float g[NE];
#pragma unroll
    for (int e = 0; e < NE; e++) g[e] = 1.f / (1.f + __expf(-acc[e]));
    int i1 = -1, i2 = -1;
    float m1 = -1e30f, m2 = -1e30f;
#pragma unroll
    for (int e = 0; e < NE; e++) {
      float v = g[e];
      if (v > m1) { m2 = m1; i2 = i1; m1 = v; i1 = e; }
      else if (v > m2) { m2 = v; i2 = e; }
    }
    float s = m1 + m2;
    topkw[t * 2 + 0] = m1 / s;
    topkw[t * 2 + 1] = m2 / s;
    topki[t * 2 + 0] = i1;
    topki[t * 2 + 1] = i2;
  }
}

// single block: count, prefix, scatter (replaces zero/offsets/fill)
__global__ void k_route(const int* __restrict__ topki, int* __restrict__ counts_g,
                        int* __restrict__ offs_g, int* __restrict__ slot_token,
                        int* __restrict__ token_slot) {
  __shared__ int cnt[NE], off[NE], fill[NE];
  int tid = threadIdx.x;
  if (tid < NE) { cnt[tid] = 0; fill[tid] = 0; }
  __syncthreads();
  for (int t = tid; t < TTOK; t += 1024) {
    atomicAdd(&cnt[topki[t * 2 + 0]], 1);
    atomicAdd(&cnt[topki[t * 2 + 1]], 1);
  }
  __syncthreads();
  if (tid == 0) {
    int s = 0;
    for (int e = 0; e < NE; e++) { off[e] = s; s += cnt[e]; }
  }
  __syncthreads();
  if (tid < NE) { counts_g[tid] = cnt[tid]; offs_g[tid] = off[tid]; }
  for (int t = tid; t < TTOK; t += 1024) {
#pragma unroll
    for (int k = 0; k < 2; k++) {
      int e = topki[t * 2 + k];
      int pos = atomicAdd(&fill[e], 1);
      int slot = off[e] + pos;
      slot_token[slot] = t;
      token_slot[t * 2 + k] = slot;
    }
  }
}

// ---------------- vectorized 64x64 transposes ----------------
// W1/W3 [DM][FF] f32 -> wb13 [z][4096][1024] bf16, W1 col n -> row (n>>4)*32+(n&15), W3 -> +16
__global__ void k_t13(const float* __restrict__ We1, const float* __restrict__ We3,
                      const float* __restrict__ Ws1, const float* __restrict__ Ws3,
                      unsigned short* __restrict__ wb13) {
  __shared__ float tile[64][68];
  int z = blockIdx.z;
  unsigned short* dst = wb13 + (size_t)z * 4096 * 1024;
  int r0 = blockIdx.y * 64;             // k (DM)
  int c0 = blockIdx.x * 64;             // n (FF)
  int tid = threadIdx.x;
  int r = tid >> 2, q = tid & 3;        // load: row r, 4 float4 at cols i*16+q*4
  int nn = tid >> 2, g = tid & 3;       // store: col n=c0+nn, k-group g (16 k's)

  const float* srcs[2] = {(blockIdx.z < 8) ? We1 + (size_t)z * DM * FF : Ws1,
                          (blockIdx.z < 8) ? We3 + (size_t)z * DM * FF : Ws3};
#pragma unroll
  for (int m = 0; m < 2; m++) {
    const float* src = srcs[m] + (size_t)(r0 + r) * FF + c0;
#pragma unroll
    for (int i = 0; i < 4; i++)
      *(f32x4*)&tile[r][i * 16 + q * 4] = *(const f32x4*)(src + i * 16 + q * 4);
    __syncthreads();
    int n = c0 + nn;
    int d = ((n >> 4) << 5) + (n & 15) + m * 16;
    ushort8 o0, o1;
#pragma unroll
    for (int j = 0; j < 8; j++) o0[j] = f2bf(tile[g * 16 + j][nn]);
#pragma unroll
    for (int j = 0; j < 8; j++) o1[j] = f2bf(tile[g * 16 + 8 + j][nn]);
    unsigned short* dp = dst + (size_t)d * 1024 + r0 + g * 16;
    *(ushort8*)dp = o0;
    *(ushort8*)(dp + 8) = o1;
    __syncthreads();
  }
}

// W2 [FF][DM] f32 -> wb2 [z][1024][2048] bf16 (plain transpose)
__global__ void k_t2(const float* __restrict__ We2, const float* __restrict__ Ws2,
                     unsigned short* __restrict__ wb2) {
  __shared__ float tile[64][68];
  int z = blockIdx.z;
  const float* src0 = (z < 8) ? We2 + (size_t)z * FF * DM : Ws2;
  unsigned short* dst = wb2 + (size_t)z * 1024 * 2048;
  int r0 = blockIdx.y * 64;             // k (FF)
  int c0 = blockIdx.x * 64;             // n (DM)
  int tid = threadIdx.x;
  int r = tid >> 2, q = tid & 3;
  int nn = tid >> 2, g = tid & 3;

  const float* src = src0 + (size_t)(r0 + r) * DM + c0;
#pragma unroll
  for (int i = 0; i < 4; i++)
    *(f32x4*)&tile[r][i * 16 + q * 4] = *(const f32x4*)(src + i * 16 + q * 4);
  __syncthreads();
  ushort8 o0, o1;
#pragma unroll
  for (int j = 0; j < 8; j++) o0[j] = f2bf(tile[g * 16 + j][nn]);
#pragma unroll
  for (int j = 0; j < 8; j++) o1[j] = f2bf(tile[g * 16 + 8 + j][nn]);
  unsigned short* dp = dst + (size_t)(c0 + nn) * 2048 + r0 + g * 16;
  *(ushort8*)dp = o0;
  *(ushort8*)(dp + 8) = o1;
}

// ---------------- 128x128 GEMM, BK=64, 4 waves, 2-phase double-buffer (T3 minimum) ----------------
// G13: A=xb gathered rows (K=1024), B=wb13 (NBROW=4096), SwiGLU epilogue -> H bf16
// !G13: A=H rows (K=2048), B=wb2 (NBROW=1024), f32 epilogue -> contrib / out
template <bool G13, int K, int NBROW>
__global__ __launch_bounds__(256, 2) void k_gemm(
    const unsigned short* __restrict__ A, const unsigned short* __restrict__ B,
    unsigned short* __restrict__ Hout, float* __restrict__ Cout, float* __restrict__ Dout,
    const int* __restrict__ slot_token, const int* __restrict__ offs,
    const int* __restrict__ counts) {
  __shared__ unsigned short As[2][128 * 64];   // 2 x 16 KiB (rows of 128B, XOR-swizzled slots)
  __shared__ unsigned short Bs[2][128 * 64];
  const int NT = K / 64;

  int e = blockIdx.z;
  int seg, cnt;
  if (e == 8) { seg = 8192; cnt = 4096; }
  else        { seg = offs[e]; cnt = counts[e]; }
  int m0 = blockIdx.y * 128;
  if (m0 >= cnt) return;
  int bn = blockIdx.x;

  int tid = threadIdx.x, lane = tid & 63, w = tid >> 6;

  // staging: issue L covers rows L*32 + w*8 + (lane>>3); LDS slot lane&7, src slot = (lane&7)^(row&7)
  int slb = (((lane & 7) ^ (lane >> 3)) << 4);
  const char* asrc[4];
  const char* bsrc[4];
#pragma unroll
  for (int L = 0; L < 4; L++) {
    int row = L * 32 + w * 8 + (lane >> 3);
    int r = m0 + row; if (r > cnt - 1) r = cnt - 1;
    long tok;
    if (G13) tok = (e == 8) ? (long)r : (long)slot_token[seg + r];
    else     tok = (long)(seg + r);
    asrc[L] = (const char*)A + ((size_t)tok * K) * 2 + slb;
    int br = bn * 128 + row;
    bsrc[L] = (const char*)B + (((size_t)e * NBROW + br) * K) * 2 + slb;
  }

#define STAGE(buf, kt) do {                                            \
    _Pragma("unroll")                                                  \
    for (int L = 0; L < 4; L++) {                                      \
      async16(asrc[L] + (size_t)(kt) * 128, &As[buf][0] + L * 2048 + w * 512); \
      async16(bsrc[L] + (size_t)(kt) * 128, &Bs[buf][0] + L * 2048 + w * 512); \
    }                                                                  \
  } while (0)

  // fragment read bases (bytes): wave (wr,wc) owns 64x64
  int wr = w >> 1, wc = w & 1;
  int rbA = (wr * 64 + (lane & 15)) * 128;
  int rbB = (wc * 64 + (lane & 15)) * 128;
  int sb0 = ((((lane >> 4) + 0) ^ (lane & 7)) << 4);
  int sb1 = ((((lane >> 4) + 4) ^ (lane & 7)) << 4);

  f32x4 acc[4][4];
#pragma unroll
  for (int i = 0; i < 4; i++)
#pragma unroll
    for (int j = 0; j < 4; j++) acc[i][j] = (f32x4){0.f, 0.f, 0.f, 0.f};

#define COMPUTE(LA, LB) do {                                                         \
    short8 Af[4], Bf[4];                                                             \
    _Pragma("unroll")                                                                \
    for (int mi = 0; mi < 4; mi++) Af[mi] = *(const short8*)((LA) + rbA + mi * 2048 + sb0); \
    _Pragma("unroll")                                                                \
    for (int nf = 0; nf < 4; nf++) Bf[nf] = *(const short8*)((LB) + rbB + nf * 2048 + sb0); \
    _Pragma("unroll")                                                                \
    for (int mi = 0; mi < 4; mi++)                                                   \
      _Pragma("unroll")                                                              \
      for (int nf = 0; nf < 4; nf++)                                                 \
        acc[mi][nf] = __builtin_amdgcn_mfma_f32_16x16x32_bf16(Af[mi], Bf[nf], acc[mi][nf], 0, 0, 0); \
    _Pragma("unroll")                                                                \
    for (int mi = 0; mi < 4; mi++) Af[mi] = *(const short8*)((LA) + rbA + mi * 2048 + sb1); \
    _Pragma("unroll")                                                                \
    for (int nf = 0; nf < 4; nf++) Bf[nf] = *(const short8*)((LB) + rbB + nf * 2048 + sb1); \
    _Pragma("unroll")                                                                \
    for (int mi = 0; mi < 4; mi++)                                                   \
      _Pragma("unroll")                                                              \
      for (int nf = 0; nf < 4; nf++)                                                 \
        acc[mi][nf] = __builtin_amdgcn_mfma_f32_16x16x32_bf16(Af[mi], Bf[nf], acc[mi][nf], 0, 0, 0); \
  } while (0)

  // prologue
  STAGE(0, 0);
  VMWAIT0();
  BAR();

  for (int kt = 0; kt < NT - 1; ++kt) {
    STAGE((kt + 1) & 1, kt + 1);       // issue next-tile loads first (overlap with compute)
    const char* LA = (const char*)&As[kt & 1][0];
    const char* LB = (const char*)&Bs[kt & 1][0];
    COMPUTE(LA, LB);
    VMWAIT0();                          // next tile landed
    BAR();                              // all reads of this buffer done; release next iteration
  }
  {
    const char* LA = (const char*)&As[(NT - 1) & 1][0];
    const char* LB = (const char*)&Bs[(NT - 1) & 1][0];
    COMPUTE(LA, LB);
  }
#undef COMPUTE
#undef STAGE

  // ---------------- epilogue ----------------
  if (G13) {
#pragma unroll
    for (int mi = 0; mi < 4; mi++)
#pragma unroll
      for (int j = 0; j < 2; j++)
#pragma unroll
        for (int q = 0; q < 4; q++) {
          int rl = wr * 64 + mi * 16 + (lane >> 4) * 4 + q;
          if (m0 + rl < cnt) {
            float s1 = acc[mi][2 * j][q], s3 = acc[mi][2 * j + 1][q];
            float h = (s1 / (1.f + __expf(-s1))) * s3;
            int nrow = bn * 128 + wc * 64 + 2 * j * 16 + (lane & 15);  // W1 row in wb13 N-space
            int ffcol = ((nrow >> 5) << 4) + (nrow & 15);
            Hout[(size_t)(seg + m0 + rl) * 2048 + ffcol] = f2bf(h);
          }
        }
  } else {
#pragma unroll
    for (int mi = 0; mi < 4; mi++)
#pragma unroll
      for (int nf = 0; nf < 4; nf++)
#pragma unroll
        for (int q = 0; q < 4; q++) {
          int rl = wr * 64 + mi * 16 + (lane >> 4) * 4 + q;
          if (m0 + rl < cnt) {
            int col = bn * 128 + wc * 64 + nf * 16 + (lane & 15);
            if (e == 8) Dout[(size_t)(m0 + rl) * 1024 + col] = acc[mi][nf][q];
            else        Cout[(size_t)(seg + m0 + rl) * 1024 + col] = acc[mi][nf][q];
          }
        }
  }
}

// out[t] = (shared[t] + w0*contrib[s0] + w1*contrib[s1]) / 3   (shared already in out)
__global__ void k_combine(float* __restrict__ out, const float* __restrict__ contrib,
                          const int* __restrict__ token_slot, const float* __restrict__ topkw) {
  int t = blockIdx.x;
  int c = threadIdx.x * 4;
  int s0 = token_slot[t * 2 + 0], s1 = token_slot[t * 2 + 1];
  float w0 = topkw[t * 2 + 0], w1 = topkw[t * 2 + 1];
  float* po = out + (size_t)t * DM + c;
  const float* p0 = contrib + (size_t)s0 * DM + c;
  const float* p1 = contrib + (size_t)s1 * DM + c;
  f32x4 vo = *(f32x4*)po;
  f32x4 v0 = *(const f32x4*)p0;
  f32x4 v1 = *(const f32x4*)p1;
#pragma unroll
  for (int i = 0; i < 4; i++)
    vo[i] = (vo[i] + w0 * v0[i] + w1 * v1[i]) * (1.f / 3.f);
  *(f32x4*)po = vo;
}

// ---------------- launcher ----------------
extern "C" void kernel_launch(void* const* d_in, const int* in_sizes, int n_in,
                              void* d_out, int out_size, void* d_ws, size_t ws_size,
                              hipStream_t stream) {
  const float* x   = (const float*)d_in[0];
  const float* Wg  = (const float*)d_in[1];
  const float* Ws1 = (const float*)d_in[2];
  const float* Ws3 = (const float*)d_in[3];
  const float* Ws2 = (const float*)d_in[4];
  const float* We1 = (const float*)d_in[5];
  const float* We3 = (const float*)d_in[6];
  const float* We2 = (const float*)d_in[7];
  float* out = (float*)d_out;

  if (ws_size < WS_NEEDED) return;

  char* w = (char*)d_ws;
  unsigned short* xb   = (unsigned short*)(w + OFF_XB);
  unsigned short* wb13 = (unsigned short*)(w + OFF_WB13);
  unsigned short* wb2  = (unsigned short*)(w + OFF_WB2);
  unsigned short* H    = (unsigned short*)(w + OFF_H);
  float* contrib       = (float*)(w + OFF_CONTRIB);
  float* topkw         = (float*)(w + OFF_TOPKW);
  int* topki           = (int*)(w + OFF_TOPKI);
  int* slot_token      = (int*)(w + OFF_SLOTTOK);
  int* token_slot      = (int*)(w + OFF_TOKSLOT);
  int* counts          = (int*)(w + OFF_COUNTS);
  int* offs            = counts + 16;

  k_gatecvt<<<TTOK / 4, 256, 0, stream>>>(x, Wg, topkw, topki, xb);
  k_route<<<1, 1024, 0, stream>>>(topki, counts, offs, slot_token, token_slot);
  k_t13<<<dim3(FF / 64, DM / 64, 9), 256, 0, stream>>>(We1, We3, Ws1, Ws3, wb13);
  k_t2<<<dim3(DM / 64, FF / 64, 9), 256, 0, stream>>>(We2, Ws2, wb2);

  k_gemm<true, 1024, 4096><<<dim3(32, 32, 9), 256, 0, stream>>>(
      xb, wb13, H, nullptr, nullptr, slot_token, offs, counts);
  k_gemm<false, 2048, 1024><<<dim3(8, 32, 9), 256, 0, stream>>>(
      H, wb2, nullptr, contrib, out, slot_token, offs, counts);

  k_combine<<<TTOK, 256, 0, stream>>>(out, contrib, token_slot, topkw);
}

// Round 5
// 320.662 us; speedup vs baseline: 1.7450x; 1.0156x over previous
//
#include <hip/hip_runtime.h>
#include <stdint.h>

#define TTOK 4096
#define DM   1024
#define FF   2048
#define NE   8

typedef __attribute__((ext_vector_type(8))) short short8;
typedef __attribute__((ext_vector_type(8))) unsigned short ushort8;
typedef __attribute__((ext_vector_type(4))) float f32x4;

// ---------------- workspace layout (bytes) ----------------
#define OFF_XB      0ull
#define OFF_WB13    (OFF_XB      + (size_t)TTOK*DM*2)          // [9][4096][1024] bf16 (W1/W3 interleaved 16-row groups)
#define OFF_WB2     (OFF_WB13    + (size_t)9*4096*1024*2)      // [9][1024][2048] bf16
#define OFF_H       (OFF_WB2     + (size_t)9*1024*2048*2)      // [12288][2048] bf16 (slots 0..8191 routed, 8192+ shared)
#define OFF_CONTRIB (OFF_H       + (size_t)12288*2048*2)       // [8192][1024] f32
#define OFF_TOPKW   (OFF_CONTRIB + (size_t)8192*1024*4)
#define OFF_TOPKI   (OFF_TOPKW   + (size_t)TTOK*2*4)
#define OFF_SLOTTOK (OFF_TOPKI   + (size_t)TTOK*2*4)
#define OFF_TOKSLOT (OFF_SLOTTOK + (size_t)TTOK*2*4)
#define OFF_COUNTS  (OFF_TOKSLOT + (size_t)TTOK*2*4)
#define WS_NEEDED   (OFF_COUNTS + 256)

#define VMWAIT(N) asm volatile("s_waitcnt vmcnt(" #N ")" ::: "memory")
#define LGKM0()   asm volatile("s_waitcnt lgkmcnt(0)" ::: "memory")
#define BAR()     __builtin_amdgcn_s_barrier()
#define SCHED0()  __builtin_amdgcn_sched_barrier(0)

__device__ __forceinline__ unsigned short f2bf(float f) {
  unsigned u = __float_as_uint(f);
  return (unsigned short)((u + 0x7FFFu + ((u >> 16) & 1u)) >> 16);
}

__device__ __forceinline__ void async16(const void* g, void* l) {
  __builtin_amdgcn_global_load_lds(
      (const __attribute__((address_space(1))) void*)g,
      (__attribute__((address_space(3))) void*)l, 16, 0, 0);
}

// ---------------- gate (fp32) + x->bf16 convert, vectorized ----------------
__global__ void k_gatecvt(const float* __restrict__ x, const float* __restrict__ Wg,
                          float* __restrict__ topkw, int* __restrict__ topki,
                          unsigned short* __restrict__ xb) {
  int wave = threadIdx.x >> 6;
  int lane = threadIdx.x & 63;
  int t = blockIdx.x * 4 + wave;
  float acc[NE];
#pragma unroll
  for (int e = 0; e < NE; e++) acc[e] = 0.f;
  const float* xr = x + (size_t)t * DM;
  unsigned short* xbr = xb + (size_t)t * DM;
#pragma unroll
  for (int i = 0; i < 4; i++) {
    int k = i * 256 + lane * 4;
    f32x4 xv = *(const f32x4*)(xr + k);
    unsigned short o0 = f2bf(xv[0]), o1 = f2bf(xv[1]), o2 = f2bf(xv[2]), o3 = f2bf(xv[3]);
    unsigned long long pk = (unsigned long long)o0 | ((unsigned long long)o1 << 16) |
                            ((unsigned long long)o2 << 32) | ((unsigned long long)o3 << 48);
    *(unsigned long long*)(xbr + k) = pk;
#pragma unroll
    for (int j = 0; j < 4; j++) {
      const float* wr = Wg + (size_t)(k + j) * NE;
#pragma unroll
      for (int e = 0; e < NE; e++) acc[e] += xv[j] * wr[e];
    }
  }
#pragma unroll
  for (int e = 0; e < NE; e++) {
#pragma unroll
    for (int off = 32; off >= 1; off >>= 1) acc[e] += __shfl_xor(acc[e], off, 64);
  }
  if (lane == 0) {
    float g[NE];
#pragma unroll
    for (int e = 0; e < NE; e++) g[e] = 1.f / (1.f + __expf(-acc[e]));
    int i1 = -1, i2 = -1;
    float m1 = -1e30f, m2 = -1e30f;
#pragma unroll
    for (int e = 0; e < NE; e++) {
      float v = g[e];
      if (v > m1) { m2 = m1; i2 = i1; m1 = v; i1 = e; }
      else if (v > m2) { m2 = v; i2 = e; }
    }
    float s = m1 + m2;
    topkw[t * 2 + 0] = m1 / s;
    topkw[t * 2 + 1] = m2 / s;
    topki[t * 2 + 0] = i1;
    topki[t * 2 + 1] = i2;
  }
}

// single block: count, prefix, scatter
__global__ void k_route(const int* __restrict__ topki, int* __restrict__ counts_g,
                        int* __restrict__ offs_g, int* __restrict__ slot_token,
                        int* __restrict__ token_slot) {
  __shared__ int cnt[NE], off[NE], fill[NE];
  int tid = threadIdx.x;
  if (tid < NE) { cnt[tid] = 0; fill[tid] = 0; }
  __syncthreads();
  for (int t = tid; t < TTOK; t += 1024) {
    atomicAdd(&cnt[topki[t * 2 + 0]], 1);
    atomicAdd(&cnt[topki[t * 2 + 1]], 1);
  }
  __syncthreads();
  if (tid == 0) {
    int s = 0;
    for (int e = 0; e < NE; e++) { off[e] = s; s += cnt[e]; }
  }
  __syncthreads();
  if (tid < NE) { counts_g[tid] = cnt[tid]; offs_g[tid] = off[tid]; }
  for (int t = tid; t < TTOK; t += 1024) {
#pragma unroll
    for (int k = 0; k < 2; k++) {
      int e = topki[t * 2 + k];
      int pos = atomicAdd(&fill[e], 1);
      int slot = off[e] + pos;
      slot_token[slot] = t;
      token_slot[t * 2 + k] = slot;
    }
  }
}

// ---------------- vectorized 64x64 transposes ----------------
// W1/W3 [DM][FF] f32 -> wb13 [z][4096][1024] bf16, W1 col n -> row (n>>4)*32+(n&15), W3 -> +16
__global__ void k_t13(const float* __restrict__ We1, const float* __restrict__ We3,
                      const float* __restrict__ Ws1, const float* __restrict__ Ws3,
                      unsigned short* __restrict__ wb13) {
  __shared__ float tile[64][68];
  int z = blockIdx.z;
  unsigned short* dst = wb13 + (size_t)z * 4096 * 1024;
  int r0 = blockIdx.y * 64;             // k (DM)
  int c0 = blockIdx.x * 64;             // n (FF)
  int tid = threadIdx.x;
  int r = tid >> 2, q = tid & 3;        // load: row r, 4 float4 at cols i*16+q*4
  int nn = tid >> 2, g = tid & 3;       // store: col n=c0+nn, k-group g (16 k's)

  const float* srcs[2] = {(blockIdx.z < 8) ? We1 + (size_t)z * DM * FF : Ws1,
                          (blockIdx.z < 8) ? We3 + (size_t)z * DM * FF : Ws3};
#pragma unroll
  for (int m = 0; m < 2; m++) {
    const float* src = srcs[m] + (size_t)(r0 + r) * FF + c0;
#pragma unroll
    for (int i = 0; i < 4; i++)
      *(f32x4*)&tile[r][i * 16 + q * 4] = *(const f32x4*)(src + i * 16 + q * 4);
    __syncthreads();
    int n = c0 + nn;
    int d = ((n >> 4) << 5) + (n & 15) + m * 16;
    ushort8 o0, o1;
#pragma unroll
    for (int j = 0; j < 8; j++) o0[j] = f2bf(tile[g * 16 + j][nn]);
#pragma unroll
    for (int j = 0; j < 8; j++) o1[j] = f2bf(tile[g * 16 + 8 + j][nn]);
    unsigned short* dp = dst + (size_t)d * 1024 + r0 + g * 16;
    *(ushort8*)dp = o0;
    *(ushort8*)(dp + 8) = o1;
    __syncthreads();
  }
}

// W2 [FF][DM] f32 -> wb2 [z][1024][2048] bf16 (plain transpose)
__global__ void k_t2(const float* __restrict__ We2, const float* __restrict__ Ws2,
                     unsigned short* __restrict__ wb2) {
  __shared__ float tile[64][68];
  int z = blockIdx.z;
  const float* src0 = (z < 8) ? We2 + (size_t)z * FF * DM : Ws2;
  unsigned short* dst = wb2 + (size_t)z * 1024 * 2048;
  int r0 = blockIdx.y * 64;             // k (FF)
  int c0 = blockIdx.x * 64;             // n (DM)
  int tid = threadIdx.x;
  int r = tid >> 2, q = tid & 3;
  int nn = tid >> 2, g = tid & 3;

  const float* src = src0 + (size_t)(r0 + r) * DM + c0;
#pragma unroll
  for (int i = 0; i < 4; i++)
    *(f32x4*)&tile[r][i * 16 + q * 4] = *(const f32x4*)(src + i * 16 + q * 4);
  __syncthreads();
  ushort8 o0, o1;
#pragma unroll
  for (int j = 0; j < 8; j++) o0[j] = f2bf(tile[g * 16 + j][nn]);
#pragma unroll
  for (int j = 0; j < 8; j++) o1[j] = f2bf(tile[g * 16 + 8 + j][nn]);
  unsigned short* dp = dst + (size_t)(c0 + nn) * 2048 + r0 + g * 16;
  *(ushort8*)dp = o0;
  *(ushort8*)(dp + 8) = o1;
}

// ---------------- 256x256 8-phase GEMM, BK=64, 8 waves (2Mx4N), counted vmcnt ----------------
// Schedule per iteration (2 K-tiles: t0=2it->buf0, t1=2it+1->buf1), phases P1..P8:
//   P1..P4 compute t0 (q=0..3), P5..P8 compute t1.  Phase q: mi {2q,2q+1} x 4nf x 2ks = 16 MFMA;
//   q==0 also loads all 8 B-frags (kept in regs for the K-tile).
// Stage calendar (1 half-tile/phase, dest retired >=1 barrier earlier):
//   P1: B1h1(t1)  P2: A1h0(t1)  P3: A1h1(t1)  P4: B0h0(t+2) + VMWAIT(2)
//   P5: B0h1(t+2) P6: A0h0(t+2) P7: A0h1(t+2) P8: B1h0(t+3) + VMWAIT(2)
// B-halves retire at their K-tile's first phase (all B read in q==0); A-halves at its last phase.
// vmcnt(2) leaves only the newest half-tile in flight => next K-tile's 4 halves have landed.
template <bool G13, int K, int NBROW>
__global__ __launch_bounds__(512, 2) void k_gemm(
    const unsigned short* __restrict__ A, const unsigned short* __restrict__ B,
    unsigned short* __restrict__ Hout, float* __restrict__ Cout, float* __restrict__ Dout,
    const int* __restrict__ slot_token, const int* __restrict__ offs,
    const int* __restrict__ counts) {
  __shared__ unsigned short lds[2][2][2][8192];   // [dbuf][A=0/B=1][half][128*64] = 128 KiB
  const int NT = K / 64;

  int e = blockIdx.z;
  int seg, cnt;
  if (e == 8) { seg = 8192; cnt = 4096; }
  else        { seg = offs[e]; cnt = counts[e]; }
  int m0 = blockIdx.y * 256;
  if (m0 >= cnt) return;
  int bn = blockIdx.x;

  int tid = threadIdx.x, lane = tid & 63, w = tid >> 6;

  // staging source pointers: thread covers rows half*128 + j*64 + (tid>>3), LDS slot tid&7,
  // source slot = (tid&7) ^ (row&7)  (row&7 == (tid>>3)&7 for all half/j)
  int srcslot = (((tid & 7) ^ ((tid >> 3) & 7)) << 4);
  const char* aptr[2][2];
  const char* bptr[2][2];
#pragma unroll
  for (int half = 0; half < 2; half++)
#pragma unroll
    for (int j = 0; j < 2; j++) {
      int rl = half * 128 + j * 64 + (tid >> 3);
      int r = m0 + rl; if (r > cnt - 1) r = cnt - 1;
      long tok;
      if (G13) tok = (e == 8) ? (long)r : (long)slot_token[seg + r];
      else     tok = (long)(seg + r);
      aptr[half][j] = (const char*)A + ((size_t)tok * K) * 2 + srcslot;
      int br = bn * 256 + rl;
      bptr[half][j] = (const char*)B + (((size_t)e * NBROW + br) * K) * 2 + srcslot;
    }

#define STG(b, op, half, kt) do {                                           \
    const char* _p0 = (op ? bptr : aptr)[half][0] + (size_t)(kt) * 128;     \
    const char* _p1 = (op ? bptr : aptr)[half][1] + (size_t)(kt) * 128;     \
    async16(_p0, &lds[b][op][half][(size_t)w * 512]);                       \
    async16(_p1, &lds[b][op][half][4096 + (size_t)w * 512]);                \
  } while (0)

  // read-side: wave (wr, wc); wr in {0,1} -> A-half = wr; wc in {0..3} -> B-half = wc>>1
  int wr = w >> 2, wc = w & 3, wch = wc >> 1;
  int s0 = (((0 + (lane >> 4)) ^ (lane & 7)) << 4);   // ks0 swizzled slot byte-offset
  int s1 = (((4 + (lane >> 4)) ^ (lane & 7)) << 4);   // ks1

  f32x4 acc[8][4];
#pragma unroll
  for (int i = 0; i < 8; i++)
#pragma unroll
    for (int j = 0; j < 4; j++) acc[i][j] = (f32x4){0.f, 0.f, 0.f, 0.f};

  short8 Af[2][2], Bf[4][2];

#define DO_PHASE(LA, LB, qq, STG_STMT, WAIT_STMT) do {                        \
    if (qq == 0) {                                                            \
      _Pragma("unroll") for (int nf = 0; nf < 4; nf++) {                      \
        int rb = ((wc & 1) * 64 + nf * 16 + (lane & 15)) * 128;               \
        Bf[nf][0] = *(const short8*)((LB) + rb + s0);                         \
        Bf[nf][1] = *(const short8*)((LB) + rb + s1);                         \
      }                                                                       \
    }                                                                         \
    _Pragma("unroll") for (int m2 = 0; m2 < 2; m2++) {                        \
      int ra = (((qq) * 2 + m2) * 16 + (lane & 15)) * 128;                    \
      Af[m2][0] = *(const short8*)((LA) + ra + s0);                           \
      Af[m2][1] = *(const short8*)((LA) + ra + s1);                           \
    }                                                                         \
    STG_STMT;                                                                 \
    BAR();                                                                    \
    LGKM0();                                                                  \
    SCHED0();                                                                 \
    __builtin_amdgcn_s_setprio(1);                                            \
    _Pragma("unroll") for (int m2 = 0; m2 < 2; m2++)                          \
      _Pragma("unroll") for (int nf = 0; nf < 4; nf++) {                      \
        acc[(qq) * 2 + m2][nf] = __builtin_amdgcn_mfma_f32_16x16x32_bf16(     \
            Af[m2][0], Bf[nf][0], acc[(qq) * 2 + m2][nf], 0, 0, 0);           \
        acc[(qq) * 2 + m2][nf] = __builtin_amdgcn_mfma_f32_16x16x32_bf16(     \
            Af[m2][1], Bf[nf][1], acc[(qq) * 2 + m2][nf], 0, 0, 0);           \
      }                                                                       \
    __builtin_amdgcn_s_setprio(0);                                            \
    WAIT_STMT;                                                                \
    BAR();                                                                    \
  } while (0)

  // prologue: K-tile0 (4 halves -> buf0) + B1h0 of K-tile1; wait leaves B1h0 in flight
  STG(0, 1, 0, 0);
  STG(0, 1, 1, 0);
  STG(0, 0, 0, 0);
  STG(0, 0, 1, 0);
  STG(1, 1, 0, 1);
  VMWAIT(2);
  BAR();

  const char* LA0 = (const char*)&lds[0][0][wr][0];
  const char* LB0 = (const char*)&lds[0][1][wch][0];
  const char* LA1 = (const char*)&lds[1][0][wr][0];
  const char* LB1 = (const char*)&lds[1][1][wch][0];

  for (int it = 0; it < NT / 2; ++it) {
    int t1 = 2 * it + 1;
    int n2 = (2 * it + 2 < NT) ? 2 * it + 2 : NT - 1;   // clamped over-stage at tail
    int n3 = (2 * it + 3 < NT) ? 2 * it + 3 : NT - 1;   // (lands in retired buffers, never read)
    DO_PHASE(LA0, LB0, 0, STG(1, 1, 1, t1), );              // P1
    DO_PHASE(LA0, LB0, 1, STG(1, 0, 0, t1), );              // P2
    DO_PHASE(LA0, LB0, 2, STG(1, 0, 1, t1), );              // P3
    DO_PHASE(LA0, LB0, 3, STG(0, 1, 0, n2), VMWAIT(2));     // P4
    DO_PHASE(LA1, LB1, 0, STG(0, 1, 1, n2), );              // P5
    DO_PHASE(LA1, LB1, 1, STG(0, 0, 0, n2), );              // P6
    DO_PHASE(LA1, LB1, 2, STG(0, 0, 1, n2), );              // P7
    DO_PHASE(LA1, LB1, 3, STG(1, 1, 0, n3), VMWAIT(2));     // P8
  }
  VMWAIT(0);
#undef DO_PHASE
#undef STG

  // ---------------- epilogue ----------------
  if (G13) {
#pragma unroll
    for (int mi = 0; mi < 8; mi++)
#pragma unroll
      for (int j = 0; j < 2; j++)
#pragma unroll
        for (int q = 0; q < 4; q++) {
          int rl = wr * 128 + mi * 16 + (lane >> 4) * 4 + q;
          if (m0 + rl < cnt) {
            float s1v = acc[mi][2 * j][q], s3v = acc[mi][2 * j + 1][q];
            float h = (s1v / (1.f + __expf(-s1v))) * s3v;
            int ffcol = (bn * 8 + wc * 2 + j) * 16 + (lane & 15);
            Hout[(size_t)(seg + m0 + rl) * 2048 + ffcol] = f2bf(h);
          }
        }
  } else {
#pragma unroll
    for (int mi = 0; mi < 8; mi++)
#pragma unroll
      for (int nf = 0; nf < 4; nf++)
#pragma unroll
        for (int q = 0; q < 4; q++) {
          int rl = wr * 128 + mi * 16 + (lane >> 4) * 4 + q;
          if (m0 + rl < cnt) {
            int col = bn * 256 + wc * 64 + nf * 16 + (lane & 15);
            if (e == 8) Dout[(size_t)(m0 + rl) * 1024 + col] = acc[mi][nf][q];
            else        Cout[(size_t)(seg + m0 + rl) * 1024 + col] = acc[mi][nf][q];
          }
        }
  }
}

// out[t] = (shared[t] + w0*contrib[s0] + w1*contrib[s1]) / 3   (shared already in out)
__global__ void k_combine(float* __restrict__ out, const float* __restrict__ contrib,
                          const int* __restrict__ token_slot, const float* __restrict__ topkw) {
  int t = blockIdx.x;
  int c = threadIdx.x * 4;
  int s0 = token_slot[t * 2 + 0], s1 = token_slot[t * 2 + 1];
  float w0 = topkw[t * 2 + 0], w1 = topkw[t * 2 + 1];
  float* po = out + (size_t)t * DM + c;
  const float* p0 = contrib + (size_t)s0 * DM + c;
  const float* p1 = contrib + (size_t)s1 * DM + c;
  f32x4 vo = *(f32x4*)po;
  f32x4 v0 = *(const f32x4*)p0;
  f32x4 v1 = *(const f32x4*)p1;
#pragma unroll
  for (int i = 0; i < 4; i++)
    vo[i] = (vo[i] + w0 * v0[i] + w1 * v1[i]) * (1.f / 3.f);
  *(f32x4*)po = vo;
}

// ---------------- launcher ----------------
extern "C" void kernel_launch(void* const* d_in, const int* in_sizes, int n_in,
                              void* d_out, int out_size, void* d_ws, size_t ws_size,
                              hipStream_t stream) {
  const float* x   = (const float*)d_in[0];
  const float* Wg  = (const float*)d_in[1];
  const float* Ws1 = (const float*)d_in[2];
  const float* Ws3 = (const float*)d_in[3];
  const float* Ws2 = (const float*)d_in[4];
  const float* We1 = (const float*)d_in[5];
  const float* We3 = (const float*)d_in[6];
  const float* We2 = (const float*)d_in[7];
  float* out = (float*)d_out;

  if (ws_size < WS_NEEDED) return;

  char* w = (char*)d_ws;
  unsigned short* xb   = (unsigned short*)(w + OFF_XB);
  unsigned short* wb13 = (unsigned short*)(w + OFF_WB13);
  unsigned short* wb2  = (unsigned short*)(w + OFF_WB2);
  unsigned short* H    = (unsigned short*)(w + OFF_H);
  float* contrib       = (float*)(w + OFF_CONTRIB);
  float* topkw         = (float*)(w + OFF_TOPKW);
  int* topki           = (int*)(w + OFF_TOPKI);
  int* slot_token      = (int*)(w + OFF_SLOTTOK);
  int* token_slot      = (int*)(w + OFF_TOKSLOT);
  int* counts          = (int*)(w + OFF_COUNTS);
  int* offs            = counts + 16;

  k_gatecvt<<<TTOK / 4, 256, 0, stream>>>(x, Wg, topkw, topki, xb);
  k_route<<<1, 1024, 0, stream>>>(topki, counts, offs, slot_token, token_slot);
  k_t13<<<dim3(FF / 64, DM / 64, 9), 256, 0, stream>>>(We1, We3, Ws1, Ws3, wb13);
  k_t2<<<dim3(DM / 64, FF / 64, 9), 256, 0, stream>>>(We2, Ws2, wb2);

  k_gemm<true, 1024, 4096><<<dim3(16, 16, 9), 512, 0, stream>>>(
      xb, wb13, H, nullptr, nullptr, slot_token, offs, counts);
  k_gemm<false, 2048, 1024><<<dim3(4, 16, 9), 512, 0, stream>>>(
      H, wb2, nullptr, contrib, out, slot_token, offs, counts);

  k_combine<<<TTOK, 256, 0, stream>>>(out, contrib, token_slot, topkw);
}